// Round 9
// baseline (1991.110 us; speedup 1.0000x reference)
//
#include <hip/hip_runtime.h>
#include <hip/hip_bf16.h>
#include <hip/hip_cooperative_groups.h>

namespace cg = cooperative_groups;

#define DEV __device__ __forceinline__

typedef __attribute__((ext_vector_type(8))) short bf16x8;
typedef __attribute__((ext_vector_type(4))) float f32x4;

DEV float bf2f(__hip_bfloat16 v) { return __bfloat162float(v); }
DEV float b2f(short u) { return __uint_as_float(((unsigned)(unsigned short)u) << 16); }
DEV float lrelu(float x) { return x > 0.f ? x : 0.2f * x; }
DEV float eluf(float x) { return x > 0.f ? x : (__expf(x) - 1.f); }

DEV unsigned short f2bf(float x) {
    unsigned int u = __float_as_uint(x);
    return (unsigned short)((u + 0x7FFFu + ((u >> 16) & 1u)) >> 16);
}

DEV float ldf(const void* p, int i, int f) {
    return f ? bf2f(((const __hip_bfloat16*)p)[i]) : ((const float*)p)[i];
}

// bf16-vs-fp32 detection (r2): low-half exponent test over 64 words.
DEV int detect_bf16(const void* p) {
    const unsigned int* w = (const unsigned int*)p;
    unsigned int e = (w[threadIdx.x & 63] >> 7) & 0xFFu;
    int hit = (e >= 112u && e <= 130u) ? 1 : 0;
    unsigned long long b = __ballot(hit);
    return __popcll(b) > 32 ? 1 : 0;
}

DEV uint4 ld8(const void* src, size_t off, int mode, int f) {
    if (mode == 0 || f) return *(const uint4*)((const unsigned short*)src + off);
    const float* s = (const float*)src + off;
    float4 a = *(const float4*)s, b = *(const float4*)(s + 4);
    uint4 r;
    r.x = f2bf(a.x) | ((unsigned)f2bf(a.y) << 16);
    r.y = f2bf(a.z) | ((unsigned)f2bf(a.w) << 16);
    r.z = f2bf(b.x) | ((unsigned)f2bf(b.y) << 16);
    r.w = f2bf(b.z) | ((unsigned)f2bf(b.w) << 16);
    return r;
}

#define P_W0 0
#define P_W1 4096
#define P_W2 12288
#define P_AS0 14336
#define P_AD0 14400
#define P_B0 14464
#define P_AS1 14528
#define P_AD1 14592
#define P_B1 14656
#define P_AS2 14720
#define P_AD2 14736
#define P_B2 14752
#define P_GAMMA 14768
#define P_BETA 14784
#define P_TOTAL 14800

#define CAP 6144
#define NBLK 1024          // edge chunks == mega grid size
#define SMSZ 35840

struct MegaArgs {
    const void* x1; const void* x2;
    const int* ei1; const int* ei2;
    const void* prm[14];
    float* P;
    int* counts; int* bfill; int* bedge;
    int *rp1, *dg1, *col1, *rp2, *dg2, *col2;
    unsigned short *h0, *h1, *hlin;
    float *as_, *ad_;
    float* logits; float* bnpart; float* bn;
    void* out;
    int N, E, nb, NB, chunk, numTiles;
};

// ---------------- device phase bodies ----------------

DEV void dev_params(const void* const* prm, float* P, int f, int b) {
    const int narr[14] = {4096, 8192, 2048, 64, 64, 64, 64, 64, 64, 16, 16, 16, 16, 16};
    const int oarr[14] = {P_W0, P_W1, P_W2, P_AS0, P_AD0, P_B0, P_AS1, P_AD1, P_B1,
                          P_AS2, P_AD2, P_B2, P_GAMMA, P_BETA};
    const void* src = prm[b];
    int nn = narr[b], oo = oarr[b];
    for (int i = threadIdx.x; i < nn; i += 256) P[oo + i] = ldf(src, i, f);
}

DEV void dev_count(const int* ei1, const int* ei2, int E, int* counts,
                   int nb, int NB, int chunk, int blk, int* lcnt) {
    int t = threadIdx.x;
    for (int b = t; b < NB; b += 256) lcnt[b] = 0;
    __syncthreads();
    int i0 = blk * chunk, i1 = min(i0 + chunk, 2 * E);
    for (int i = i0 + t; i < i1; i += 256) {
        int b;
        if (i < E) b = ei1[E + i] >> 8;
        else       b = (ei2[i] >> 8) + nb;
        atomicAdd(&lcnt[b], 1);
    }
    __syncthreads();
    for (int b = t; b < NB; b += 256) counts[(size_t)b * NBLK + blk] = lcnt[b];
}

// 1024-wide exclusive scan per bucket (256 thr x 4 elems)
DEV void dev_scan(int* counts, int* bfill, int b, int* ps) {
    int t = threadIdx.x;
    int* row = counts + (size_t)b * NBLK;
    int x0 = row[4 * t], x1 = row[4 * t + 1], x2 = row[4 * t + 2], x3 = row[4 * t + 3];
    int tsum = x0 + x1 + x2 + x3;
    ps[t] = tsum;
    __syncthreads();
    #pragma unroll
    for (int off = 1; off < 256; off <<= 1) {
        int v = (t >= off) ? ps[t - off] : 0;
        __syncthreads();
        ps[t] += v;
        __syncthreads();
    }
    int excl = ps[t] - tsum;
    row[4 * t] = excl;
    row[4 * t + 1] = excl + x0;
    row[4 * t + 2] = excl + x0 + x1;
    row[4 * t + 3] = excl + x0 + x1 + x2;
    if (t == 255) bfill[b] = ps[255];
}

DEV void dev_place(const int* ei1, const int* ei2, int E, const int* counts,
                   int* bedge, int nb, int NB, int chunk, int blk, int* lbase) {
    int t = threadIdx.x;
    for (int b = t; b < NB; b += 256) lbase[b] = counts[(size_t)b * NBLK + blk];
    __syncthreads();
    int i0 = blk * chunk, i1 = min(i0 + chunk, 2 * E);
    for (int i = i0 + t; i < i1; i += 256) {
        int s, d, b;
        if (i < E) { s = ei1[i]; d = ei1[E + i]; b = d >> 8; }
        else       { s = ei2[i - E]; d = ei2[i]; b = (d >> 8) + nb; }
        int pos = atomicAdd(&lbase[b], 1);
        if (pos < CAP) bedge[(size_t)b * CAP + pos] = (s << 8) | (d & 255);
    }
}

DEV void dev_bucket2(const int* bfillA, const int* bedgeA,
                     int* rp1, int* dg1, int* col1,
                     int* rp2, int* dg2, int* col2,
                     int nb, int N, int b, char* smraw) {
    const int* bfill; const int* bedge; int* rowptr; int* deg; int* col;
    int bb = b;
    if (bb < nb) { bfill = bfillA; bedge = bedgeA; rowptr = rp1; deg = dg1; col = col1; }
    else { bb -= nb; bfill = bfillA + nb; bedge = bedgeA + (size_t)nb * CAP;
           rowptr = rp2; deg = dg2; col = col2; }

    int* ldeg = (int*)smraw;
    int* lscan = ldeg + 256;
    int* lfill = ldeg + 512;
    int t = threadIdx.x;
    ldeg[t] = 0;
    __syncthreads();

    int cnt = min(bfill[bb], CAP);
    const int* be = bedge + (size_t)bb * CAP;
    for (int e = t; e < cnt; e += 256) atomicAdd(&ldeg[be[e] & 255], 1);
    __syncthreads();

    int myDeg = ldeg[t];
    lscan[t] = myDeg;
    __syncthreads();
    #pragma unroll
    for (int off = 1; off < 256; off <<= 1) {
        int v = (t >= off) ? lscan[t - off] : 0;
        __syncthreads();
        lscan[t] += v;
        __syncthreads();
    }
    int excl = lscan[t] - myDeg;
    int node = (bb << 8) + t;
    int base = bb * CAP;
    if (node < N) { rowptr[node] = base + excl; deg[node] = myDeg; }
    lfill[t] = excl;
    __syncthreads();

    for (int e = t; e < cnt; e += 256) {
        int ed = be[e];
        int pos = atomicAdd(&lfill[ed & 255], 1);
        col[base + pos] = ed >> 8;
    }
}

template <int K, int C>
DEV void dev_gemm(const void* A1, int mode1, const void* A2, int mode2,
                  const float* W, const float* av, const float* dv,
                  unsigned short* Hout, float* as_, float* ad_,
                  int N, int numTiles, int f, int bid, int stride, char* smraw) {
    constexpr int KP = K + 8;
    constexpr int KK = K / 32;
    constexpr int CT = C / 16;
    constexpr int G  = K / 8;

    short* As = (short*)smraw;           // 64*KP shorts
    short* Wt = As + 64 * KP;            // C*KP shorts
    float* avs = (float*)(Wt + C * KP);
    float* dvs = avs + C;

    int t = threadIdx.x;
    for (int idx = t; idx < K * C; idx += 256) {
        int k = idx / C, n = idx % C;
        Wt[n * KP + k] = (short)f2bf(W[idx]);
    }
    for (int i = t; i < C; i += 256) { avs[i] = av[i]; dvs[i] = dv[i]; }
    __syncthreads();

    const int lane = t & 63, w = t >> 6;
    const int m = lane & 15, q = lane >> 4;

    bf16x8 bfr[KK][CT];
    #pragma unroll
    for (int kk = 0; kk < KK; kk++)
        #pragma unroll
        for (int ct = 0; ct < CT; ct++)
            bfr[kk][ct] = *(const bf16x8*)&Wt[(ct * 16 + m) * KP + kk * 32 + q * 8];

    for (int tile = bid; tile < numTiles; tile += stride) {
        __syncthreads();
        int rowBase = tile * 64;
        for (int idx = t; idx < 64 * G; idx += 256) {
            int r = idx / G, g = idx % G;
            int row = rowBase + r;
            uint4 val = {0u, 0u, 0u, 0u};
            if (row < N) {
                if (g < 8) val = ld8(A1, (size_t)row * 64 + g * 8, mode1, f);
                else       val = ld8(A2, (size_t)row * 64 + (g - 8) * 8, mode2, f);
            }
            *(uint4*)&As[r * KP + g * 8] = val;
        }
        __syncthreads();

        f32x4 acc[CT];
        #pragma unroll
        for (int ct = 0; ct < CT; ct++) acc[ct] = (f32x4){0.f, 0.f, 0.f, 0.f};

        #pragma unroll
        for (int kk = 0; kk < KK; kk++) {
            bf16x8 a = *(const bf16x8*)&As[(w * 16 + m) * KP + kk * 32 + q * 8];
            #pragma unroll
            for (int ct = 0; ct < CT; ct++)
                acc[ct] = __builtin_amdgcn_mfma_f32_16x16x32_bf16(a, bfr[kk][ct], acc[ct], 0, 0, 0);
        }

        #pragma unroll
        for (int r = 0; r < 4; r++) {
            int grow = rowBase + w * 16 + q * 4 + r;
            float vs = 0.f, vd = 0.f;
            #pragma unroll
            for (int ct = 0; ct < CT; ct++) {
                float v = acc[ct][r];
                vs += v * avs[ct * 16 + m];
                vd += v * dvs[ct * 16 + m];
                if (grow < N) Hout[(size_t)grow * C + ct * 16 + m] = f2bf(v);
            }
            vs += __shfl_xor(vs, 1); vs += __shfl_xor(vs, 2);
            vs += __shfl_xor(vs, 4); vs += __shfl_xor(vs, 8);
            vd += __shfl_xor(vd, 1); vd += __shfl_xor(vd, 2);
            vd += __shfl_xor(vd, 4); vd += __shfl_xor(vd, 8);
            if (grow < N && m == 0) { as_[grow] = vs; ad_[grow] = vd; }
        }
    }
}

DEV void dev_agg64(const int* rowptr, const int* deg, const int* col,
                   const float* as_, const float* ad_, const unsigned short* h,
                   const float* bias, unsigned short* out, int N, int doElu,
                   int bid, int nblocks) {
    int t = threadIdx.x;
    int lane = t & 63;
    int gw = bid * 4 + (t >> 6);
    int wstride = nblocks * 4;
    for (int wid = gw; wid < N; wid += wstride) {
        int start = rowptr[wid];
        int d = deg[wid];
        float adi = ad_[wid];
        float eself = __expf(lrelu(as_[wid] + adi));

        int dc = min(d, 64);
        float w = 0.f; int s = 0;
        if (lane < dc) { s = col[start + lane]; w = __expf(lrelu(as_[s] + adi)); }
        float ssum = w;
        for (int j = lane + 64; j < d; j += 64)
            ssum += __expf(lrelu(as_[col[start + j]] + adi));
        #pragma unroll
        for (int off = 32; off; off >>= 1) ssum += __shfl_xor(ssum, off);
        float inv = 1.f / (ssum + eself + 1e-16f);
        w *= inv;

        int fq = lane & 7, eg = lane >> 3;
        float acc[8] = {0.f, 0.f, 0.f, 0.f, 0.f, 0.f, 0.f, 0.f};
        if (eg == 0) {
            bf16x8 hv = *(const bf16x8*)&h[(size_t)wid * 64 + fq * 8];
            float en = eself * inv;
            #pragma unroll
            for (int i = 0; i < 8; i++) acc[i] = en * b2f(hv[i]);
        }
        {
            int iters = (dc + 7) >> 3;
            for (int it = 0; it < iters; it++) {
                int j = it * 8 + eg;
                float wj = __shfl(w, j);
                int sj = __shfl(s, j);
                if (j < dc) {
                    bf16x8 hv = *(const bf16x8*)&h[(size_t)sj * 64 + fq * 8];
                    #pragma unroll
                    for (int i = 0; i < 8; i++) acc[i] += wj * b2f(hv[i]);
                }
            }
        }
        for (int base = 64; base < d; base += 64) {
            int cnt = min(64, d - base);
            float w2 = 0.f; int s2 = 0;
            if (lane < cnt) { s2 = col[start + base + lane]; w2 = __expf(lrelu(as_[s2] + adi)) * inv; }
            int iters = (cnt + 7) >> 3;
            for (int it = 0; it < iters; it++) {
                int j = it * 8 + eg;
                float wj = __shfl(w2, j);
                int sj = __shfl(s2, j);
                if (j < cnt) {
                    bf16x8 hv = *(const bf16x8*)&h[(size_t)sj * 64 + fq * 8];
                    #pragma unroll
                    for (int i = 0; i < 8; i++) acc[i] += wj * b2f(hv[i]);
                }
            }
        }
        #pragma unroll
        for (int off = 8; off < 64; off <<= 1)
            #pragma unroll
            for (int i = 0; i < 8; i++) acc[i] += __shfl_xor(acc[i], off);

        if (lane < 8) {
            unsigned int res[4];
            #pragma unroll
            for (int i = 0; i < 4; i++) {
                float o0 = acc[2 * i] + bias[fq * 8 + 2 * i];
                float o1 = acc[2 * i + 1] + bias[fq * 8 + 2 * i + 1];
                if (doElu) { o0 = eluf(o0); o1 = eluf(o1); }
                res[i] = (unsigned)f2bf(o0) | ((unsigned)f2bf(o1) << 16);
            }
            *(uint4*)&out[(size_t)wid * 64 + fq * 8] = *(uint4*)res;
        }
    }
}

DEV void dev_agg16(const int* rowptr, const int* deg, const int* col,
                   const float* as_, const float* ad_, const unsigned short* h,
                   const float* bias, float* out, int N, int bid, int nblocks) {
    int t = threadIdx.x;
    int lane = t & 63;
    int gw = bid * 4 + (t >> 6);
    int wstride = nblocks * 4;
    for (int wid = gw; wid < N; wid += wstride) {
        int start = rowptr[wid];
        int d = deg[wid];
        float adi = ad_[wid];
        float eself = __expf(lrelu(as_[wid] + adi));

        int dc = min(d, 64);
        float w = 0.f; int s = 0;
        if (lane < dc) { s = col[start + lane]; w = __expf(lrelu(as_[s] + adi)); }
        float ssum = w;
        for (int j = lane + 64; j < d; j += 64)
            ssum += __expf(lrelu(as_[col[start + j]] + adi));
        #pragma unroll
        for (int off = 32; off; off >>= 1) ssum += __shfl_xor(ssum, off);
        float inv = 1.f / (ssum + eself + 1e-16f);
        w *= inv;

        int fq = lane & 1, eg = lane >> 1;
        float acc[8] = {0.f, 0.f, 0.f, 0.f, 0.f, 0.f, 0.f, 0.f};
        if (eg == 0) {
            bf16x8 hv = *(const bf16x8*)&h[(size_t)wid * 16 + fq * 8];
            float en = eself * inv;
            #pragma unroll
            for (int i = 0; i < 8; i++) acc[i] = en * b2f(hv[i]);
        }
        {
            int iters = (dc + 31) >> 5;
            for (int it = 0; it < iters; it++) {
                int j = it * 32 + eg;
                float wj = __shfl(w, j);
                int sj = __shfl(s, j);
                if (j < dc) {
                    bf16x8 hv = *(const bf16x8*)&h[(size_t)sj * 16 + fq * 8];
                    #pragma unroll
                    for (int i = 0; i < 8; i++) acc[i] += wj * b2f(hv[i]);
                }
            }
        }
        for (int base = 64; base < d; base += 64) {
            int cnt = min(64, d - base);
            float w2 = 0.f; int s2 = 0;
            if (lane < cnt) { s2 = col[start + base + lane]; w2 = __expf(lrelu(as_[s2] + adi)) * inv; }
            int iters = (cnt + 31) >> 5;
            for (int it = 0; it < iters; it++) {
                int j = it * 32 + eg;
                float wj = __shfl(w2, j);
                int sj = __shfl(s2, j);
                if (j < cnt) {
                    bf16x8 hv = *(const bf16x8*)&h[(size_t)sj * 16 + fq * 8];
                    #pragma unroll
                    for (int i = 0; i < 8; i++) acc[i] += wj * b2f(hv[i]);
                }
            }
        }
        #pragma unroll
        for (int off = 2; off < 64; off <<= 1)
            #pragma unroll
            for (int i = 0; i < 8; i++) acc[i] += __shfl_xor(acc[i], off);

        if (lane < 2) {
            float4 o0, o1;
            o0.x = acc[0] + bias[fq * 8 + 0]; o0.y = acc[1] + bias[fq * 8 + 1];
            o0.z = acc[2] + bias[fq * 8 + 2]; o0.w = acc[3] + bias[fq * 8 + 3];
            o1.x = acc[4] + bias[fq * 8 + 4]; o1.y = acc[5] + bias[fq * 8 + 5];
            o1.z = acc[6] + bias[fq * 8 + 6]; o1.w = acc[7] + bias[fq * 8 + 7];
            *(float4*)&out[(size_t)wid * 16 + fq * 8] = o0;
            *(float4*)&out[(size_t)wid * 16 + fq * 8 + 4] = o1;
        }
    }
}

// atomic-free BN stats: per-block partials, then one-block reduce
DEV void dev_bnstat(const float* logits, float* bnpart, int N, int bid, int nblocks,
                    float* lbn) {
    int t = threadIdx.x;
    if (t < 32) lbn[t] = 0.f;
    __syncthreads();
    int c = t & 15;
    int g = (bid * 256 + t) >> 4;
    int stride = (nblocks * 256) >> 4;
    float s = 0.f, s2 = 0.f;
    for (int r = g; r < N; r += stride) {
        float v = logits[(size_t)r * 16 + c];
        s += v;
        s2 += v * v;
    }
    s += __shfl_xor(s, 16);  s += __shfl_xor(s, 32);
    s2 += __shfl_xor(s2, 16); s2 += __shfl_xor(s2, 32);
    if ((t & 63) < 16) { atomicAdd(&lbn[c], s); atomicAdd(&lbn[16 + c], s2); }
    __syncthreads();
    if (t < 32) bnpart[bid * 32 + t] = lbn[t];
}

DEV void dev_bnred(const float* bnpart, float* bn, int nparts, float* part) {
    int t = threadIdx.x;
    int c = t & 31, seg = t >> 5;
    float s = 0.f;
    for (int i = seg; i < nparts; i += 8) s += bnpart[i * 32 + c];
    part[t] = s;
    __syncthreads();
    if (t < 32) {
        float tot = 0.f;
        #pragma unroll
        for (int j = 0; j < 8; j++) tot += part[t + 32 * j];
        bn[t] = tot;
    }
}

DEV void dev_final(const float* logits, const float* bn, const float* gamma,
                   const float* beta, int f, void* out, int N, int bid, int nblocks) {
    int stride = nblocks * 256;
    for (int r = bid * 256 + threadIdx.x; r < N; r += stride) {
        float invN = 1.f / (float)N;
        float y[16];
        float mx = -1e30f;
        #pragma unroll
        for (int c = 0; c < 16; c++) {
            float mu = bn[c] * invN;
            float var = bn[16 + c] * invN - mu * mu;
            float v = (logits[(size_t)r * 16 + c] - mu) * rsqrtf(var + 1e-5f);
            v = v * gamma[c] + beta[c];
            y[c] = v;
            mx = fmaxf(mx, v);
        }
        float se = 0.f;
        #pragma unroll
        for (int c = 0; c < 16; c++) se += __expf(y[c] - mx);
        float lse = mx + __logf(se);
        #pragma unroll
        for (int c = 0; c < 16; c++) {
            float v = y[c] - lse;
            if (f) ((__hip_bfloat16*)out)[(size_t)r * 16 + c] = __float2bfloat16(v);
            else   ((float*)out)[(size_t)r * 16 + c] = v;
        }
    }
}

// ---------------- cooperative mega-kernel ----------------

__global__ __launch_bounds__(256, 4) void k_mega(MegaArgs a) {
    cg::grid_group grid = cg::this_grid();
    __shared__ alignas(16) char smraw[SMSZ];
    int bid = blockIdx.x;
    const int GR = gridDim.x;
    int f = detect_bf16(a.x1);

    // A: params (blocks 0..13) + histogram count (all blocks)
    if (bid < 14) dev_params(a.prm, a.P, f, bid);
    dev_count(a.ei1, a.ei2, a.E, a.counts, a.nb, a.NB, a.chunk, bid, (int*)smraw);
    grid.sync();
    // B: per-bucket scan of block counts
    if (bid < a.NB) dev_scan(a.counts, a.bfill, bid, (int*)smraw);
    grid.sync();
    // C: deterministic placement into bucket streams
    dev_place(a.ei1, a.ei2, a.E, a.counts, a.bedge, a.nb, a.NB, a.chunk, bid, (int*)smraw);
    grid.sync();
    // D: per-bucket node sort -> CSR
    if (bid < a.NB) dev_bucket2(a.bfill, a.bedge, a.rp1, a.dg1, a.col1,
                                a.rp2, a.dg2, a.col2, a.nb, a.N, bid, smraw);
    grid.sync();
    // E: layer-0 GEMM
    dev_gemm<64, 64>(a.x1, 1, a.x1, 0, a.P + P_W0, a.P + P_AS0, a.P + P_AD0,
                     a.hlin, a.as_, a.ad_, a.N, a.numTiles, f, bid, GR, smraw);
    grid.sync();
    // F: layer-0 aggregate (graph1) -> h0
    dev_agg64(a.rp1, a.dg1, a.col1, a.as_, a.ad_, a.hlin, a.P + P_B0, a.h0, a.N, 1, bid, GR);
    grid.sync();
    // G: layer-1 GEMM
    dev_gemm<128, 64>(a.h0, 0, a.x2, 1, a.P + P_W1, a.P + P_AS1, a.P + P_AD1,
                      a.hlin, a.as_, a.ad_, a.N, a.numTiles, f, bid, GR, smraw);
    grid.sync();
    // H: layer-1 aggregate (graph2) -> h1
    dev_agg64(a.rp2, a.dg2, a.col2, a.as_, a.ad_, a.hlin, a.P + P_B1, a.h1, a.N, 1, bid, GR);
    grid.sync();
    // I: layer-2 GEMM
    dev_gemm<128, 16>(a.h0, 0, a.h1, 0, a.P + P_W2, a.P + P_AS2, a.P + P_AD2,
                      a.hlin, a.as_, a.ad_, a.N, a.numTiles, f, bid, GR, smraw);
    grid.sync();
    // J: layer-2 aggregate -> logits
    dev_agg16(a.rp2, a.dg2, a.col2, a.as_, a.ad_, a.hlin, a.P + P_B2, a.logits, a.N, bid, GR);
    grid.sync();
    // K: BN partials
    dev_bnstat(a.logits, a.bnpart, a.N, bid, GR, (float*)smraw);
    grid.sync();
    // L: BN reduce
    if (bid == 0) dev_bnred(a.bnpart, a.bn, GR, (float*)smraw);
    grid.sync();
    // M: BN apply + log_softmax
    dev_final(a.logits, a.bn, a.P + P_GAMMA, a.P + P_BETA, f, a.out, a.N, bid, GR);
}

// ---------------- fallback per-phase kernels (same device bodies) ----------------

__global__ __launch_bounds__(256) void k_wParams(MegaArgs a) {
    int f = detect_bf16(a.x1);
    dev_params(a.prm, a.P, f, blockIdx.x);
}
__global__ __launch_bounds__(256) void k_wCount(MegaArgs a) {
    __shared__ int lcnt[NBLK];
    dev_count(a.ei1, a.ei2, a.E, a.counts, a.nb, a.NB, a.chunk, blockIdx.x, lcnt);
}
__global__ __launch_bounds__(256) void k_wScan(MegaArgs a) {
    __shared__ int ps[256];
    dev_scan(a.counts, a.bfill, blockIdx.x, ps);
}
__global__ __launch_bounds__(256) void k_wPlace(MegaArgs a) {
    __shared__ int lbase[NBLK];
    dev_place(a.ei1, a.ei2, a.E, a.counts, a.bedge, a.nb, a.NB, a.chunk, blockIdx.x, lbase);
}
__global__ __launch_bounds__(256) void k_wBucket(MegaArgs a) {
    __shared__ char sm[3 * 256 * 4];
    dev_bucket2(a.bfill, a.bedge, a.rp1, a.dg1, a.col1, a.rp2, a.dg2, a.col2,
                a.nb, a.N, blockIdx.x, sm);
}
__global__ __launch_bounds__(256) void k_wGemm0(MegaArgs a) {
    __shared__ alignas(16) char sm[SMSZ];
    int f = detect_bf16(a.x1);
    dev_gemm<64, 64>(a.x1, 1, a.x1, 0, a.P + P_W0, a.P + P_AS0, a.P + P_AD0,
                     a.hlin, a.as_, a.ad_, a.N, a.numTiles, f, blockIdx.x, gridDim.x, sm);
}
__global__ __launch_bounds__(256) void k_wGemm1(MegaArgs a) {
    __shared__ alignas(16) char sm[SMSZ];
    int f = detect_bf16(a.x1);
    dev_gemm<128, 64>(a.h0, 0, a.x2, 1, a.P + P_W1, a.P + P_AS1, a.P + P_AD1,
                      a.hlin, a.as_, a.ad_, a.N, a.numTiles, f, blockIdx.x, gridDim.x, sm);
}
__global__ __launch_bounds__(256) void k_wGemm2(MegaArgs a) {
    __shared__ alignas(16) char sm[SMSZ];
    int f = detect_bf16(a.x1);
    dev_gemm<128, 16>(a.h0, 0, a.h1, 0, a.P + P_W2, a.P + P_AS2, a.P + P_AD2,
                      a.hlin, a.as_, a.ad_, a.N, a.numTiles, f, blockIdx.x, gridDim.x, sm);
}
__global__ __launch_bounds__(256) void k_wAgg64(MegaArgs a, int sel) {
    if (sel == 0)
        dev_agg64(a.rp1, a.dg1, a.col1, a.as_, a.ad_, a.hlin, a.P + P_B0, a.h0,
                  a.N, 1, blockIdx.x, gridDim.x);
    else
        dev_agg64(a.rp2, a.dg2, a.col2, a.as_, a.ad_, a.hlin, a.P + P_B1, a.h1,
                  a.N, 1, blockIdx.x, gridDim.x);
}
__global__ __launch_bounds__(256) void k_wAgg16(MegaArgs a) {
    dev_agg16(a.rp2, a.dg2, a.col2, a.as_, a.ad_, a.hlin, a.P + P_B2, a.logits,
              a.N, blockIdx.x, gridDim.x);
}
__global__ __launch_bounds__(256) void k_wBnstat(MegaArgs a) {
    __shared__ float lbn[32];
    dev_bnstat(a.logits, a.bnpart, a.N, blockIdx.x, gridDim.x, lbn);
}
__global__ __launch_bounds__(256) void k_wBnred(MegaArgs a, int nparts) {
    __shared__ float part[256];
    dev_bnred(a.bnpart, a.bn, nparts, part);
}
__global__ __launch_bounds__(256) void k_wFinal(MegaArgs a) {
    int f = detect_bf16(a.x1);
    dev_final(a.logits, a.bn, a.P + P_GAMMA, a.P + P_BETA, f, a.out, a.N,
              blockIdx.x, gridDim.x);
}

// ---------------- launch ----------------

extern "C" void kernel_launch(void* const* d_in, const int* in_sizes, int n_in,
                              void* d_out, int out_size, void* d_ws, size_t ws_size,
                              hipStream_t stream) {
    const void* x1  = d_in[0];
    const void* x2  = d_in[1];
    const int*  ei1 = (const int*)d_in[2];
    const int*  ei2 = (const int*)d_in[3];

    const int N = in_sizes[0] / 64;
    const int E = in_sizes[2] / 2;
    const int nb = (N + 255) >> 8;
    const int NB = 2 * nb;
    const int GRID = 1024;
    const int chunk = (2 * E + NBLK - 1) / NBLK;

    char* p = (char*)d_ws;
    auto alloc = [&](size_t bytes) {
        void* q = (void*)p;
        p += (bytes + 255) & ~(size_t)255;
        return q;
    };
    MegaArgs a;
    a.x1 = x1; a.x2 = x2; a.ei1 = ei1; a.ei2 = ei2;
    a.bn      = (float*)alloc(256);
    a.h0      = (unsigned short*)alloc((size_t)N * 64 * 2);
    a.h1      = (unsigned short*)alloc((size_t)N * 64 * 2);
    a.hlin    = (unsigned short*)alloc((size_t)N * 64 * 2);
    a.as_     = (float*)alloc((size_t)N * 4);
    a.ad_     = (float*)alloc((size_t)N * 4);
    a.rp1     = (int*)alloc((size_t)N * 4);
    a.dg1     = (int*)alloc((size_t)N * 4);
    a.rp2     = (int*)alloc((size_t)N * 4);
    a.dg2     = (int*)alloc((size_t)N * 4);
    a.col1    = (int*)alloc((size_t)nb * CAP * 4);   // aliased as logits after layer-0 agg
    a.col2    = (int*)alloc((size_t)nb * CAP * 4);
    a.counts  = (int*)alloc((size_t)NB * NBLK * 4);
    a.bfill   = (int*)alloc((size_t)NB * 4);
    a.bnpart  = (float*)alloc((size_t)GRID * 32 * 4);
    a.P       = (float*)alloc(P_TOTAL * 4);
    a.logits  = (float*)a.col1;
    a.bedge   = (int*)a.h0;     // NB*CAP*4 = 19.2MB aliases h0+h1 (25.6MB); dead before h writes
    a.out     = d_out;
    a.N = N; a.E = E; a.nb = nb; a.NB = NB; a.chunk = chunk;
    a.numTiles = (N + 63) / 64;

    a.prm[0] = d_in[4];  a.prm[1] = d_in[8];   a.prm[2] = d_in[12];
    a.prm[3] = d_in[5];  a.prm[4] = d_in[6];   a.prm[5] = d_in[7];
    a.prm[6] = d_in[9];  a.prm[7] = d_in[10];  a.prm[8] = d_in[11];
    a.prm[9] = d_in[13]; a.prm[10] = d_in[14]; a.prm[11] = d_in[15];
    a.prm[12] = d_in[16]; a.prm[13] = d_in[17];

    void* kargs[] = {(void*)&a};
    hipError_t err = hipLaunchCooperativeKernel((const void*)k_mega, dim3(GRID), dim3(256),
                                                kargs, 0, stream);
    if (err == hipSuccess) return;

    // Deterministic fallback: same phases as separate kernels (r8-equivalent path).
    const int TB = 256;
    int gW = (N + 3) / 4;
    int gN = (N + TB - 1) / TB;
    k_wParams<<<14, TB, 0, stream>>>(a);
    k_wCount<<<NBLK, TB, 0, stream>>>(a);
    k_wScan<<<NB, TB, 0, stream>>>(a);
    k_wPlace<<<NBLK, TB, 0, stream>>>(a);
    k_wBucket<<<NB, TB, 0, stream>>>(a);
    k_wGemm0<<<512, TB, 0, stream>>>(a);
    k_wAgg64<<<gW, TB, 0, stream>>>(a, 0);
    k_wGemm1<<<512, TB, 0, stream>>>(a);
    k_wAgg64<<<gW, TB, 0, stream>>>(a, 1);
    k_wGemm2<<<512, TB, 0, stream>>>(a);
    k_wAgg16<<<gW, TB, 0, stream>>>(a);
    k_wBnstat<<<256, TB, 0, stream>>>(a);
    k_wBnred<<<1, TB, 0, stream>>>(a, 256);
    k_wFinal<<<gN, TB, 0, stream>>>(a);
}